// Round 1
// baseline (312.297 us; speedup 1.0000x reference)
//
#include <hip/hip_runtime.h>
#include <hip/hip_bf16.h>

// SlicingLinearBlock: out[16384,4096] = x[16384,256] @ B[256,4096] (fp32),
// where B[k,o] = W[k/8, o, k%8].  Strategy: pre-convert x and W to bf16 in
// d_ws, then 128x128 bf16 MFMA GEMM, BK=64 double-buffered 2-phase pipeline
// (prefetch next K-tile via global_load_lds before computing current one),
// swapped-operand MFMA so the epilogue is float4 stores.
//
// Workspace layout (d_ws): [0, 8MB) x_bf16 [16384,256]; [8MB, 10MB) Bt_bf16 [4096,256].

typedef __attribute__((ext_vector_type(8)))  __bf16          bf16x8;
typedef __attribute__((ext_vector_type(8)))  unsigned short  ushort8;
typedef __attribute__((ext_vector_type(4)))  float           floatx4;

__device__ __forceinline__ unsigned short f2bf(float f) {
    union { float f; unsigned u; } v; v.f = f;
    unsigned r = v.u + 0x7fffu + ((v.u >> 16) & 1u);   // RNE
    return (unsigned short)(r >> 16);
}

// x [16384,256] fp32 -> bf16, 8 elements/thread, fully coalesced.
__global__ void conv_x_kernel(const float* __restrict__ x,
                              unsigned short* __restrict__ xb) {
    const int t = blockIdx.x * 256 + threadIdx.x;      // 524288 threads
    const float4* p = (const float4*)x;
    float4 a = p[2 * t], b = p[2 * t + 1];
    ushort8 v;
    v[0] = f2bf(a.x); v[1] = f2bf(a.y); v[2] = f2bf(a.z); v[3] = f2bf(a.w);
    v[4] = f2bf(b.x); v[5] = f2bf(b.y); v[6] = f2bf(b.z); v[7] = f2bf(b.w);
    *(ushort8*)(xb + (size_t)t * 8) = v;
}

// W [32,4096,8] fp32 -> Bt [4096,256] bf16, Bt[o][s*8+c] = W[s][o][c].
__global__ void pack_w_kernel(const float* __restrict__ W,
                              unsigned short* __restrict__ wb) {
    const int t = blockIdx.x * 256 + threadIdx.x;      // 131072 threads
    const int s = t >> 12;                             // 0..31
    const int o = t & 4095;
    const float4* p = (const float4*)(W + (size_t)s * 32768 + (size_t)o * 8);
    float4 a = p[0], b = p[1];
    ushort8 v;
    v[0] = f2bf(a.x); v[1] = f2bf(a.y); v[2] = f2bf(a.z); v[3] = f2bf(a.w);
    v[4] = f2bf(b.x); v[5] = f2bf(b.y); v[6] = f2bf(b.z); v[7] = f2bf(b.w);
    *(ushort8*)(wb + (size_t)o * 256 + (size_t)s * 8) = v;
}

__device__ __forceinline__ void gload_lds16(const unsigned short* g, unsigned short* l) {
    __builtin_amdgcn_global_load_lds(
        (const __attribute__((address_space(1))) unsigned int*)(const void*)g,
        (__attribute__((address_space(3))) unsigned int*)(void*)l,
        16, 0, 0);
}

// Stage one 128x64 bf16 tile pair (A,B) into LDS. Ag/Bg are per-thread
// (row = base + wave*8 + lane>>3, col pre-swizzled); la/lb wave-uniform.
__device__ __forceinline__ void stage_tile(const unsigned short* Ag,
                                           const unsigned short* Bg,
                                           unsigned short* la,
                                           unsigned short* lb) {
#pragma unroll
    for (int j = 0; j < 4; ++j) {
        gload_lds16(Ag + j * 32 * 256, la + j * 32 * 64);
        gload_lds16(Bg + j * 32 * 256, lb + j * 32 * 64);
    }
}

// C[M=16384, N=4096] fp32 = A[M,256]bf16 * Bt[N,256]bf16^T
// 128x128 tile, BK=64 double-buffered, 4 waves 2x2, each wave 64x64 via
// 4x4 of 16x16x32 MFMA (operand-swapped: acc holds C^T fragments so each
// lane owns 4 consecutive output columns -> float4 stores).
__global__ __launch_bounds__(256) void gemm_kernel(
    const unsigned short* __restrict__ A,
    const unsigned short* __restrict__ Bt,
    float* __restrict__ C) {
    // 2 buffers x (128 rows x 64 cols) x bf16 = 16 KB each => 64 KB total.
    __shared__ __align__(16) unsigned short lsA[2][128 * 64];
    __shared__ __align__(16) unsigned short lsB[2][128 * 64];

    const int tid  = threadIdx.x;
    const int wave = tid >> 6;
    const int lane = tid & 63;
    const int bm   = blockIdx.y;     // 0..127
    const int bn   = blockIdx.x;     // 0..31

    // --- staging addressing ---
    // Row within tile: wave*8 + lane>>3 (+ j*32 per call). Row = 64 cols = 8
    // chunks of 16B. LDS dest is linear (slot = lane&7); the global source
    // chunk is XOR-pre-swizzled by row&7 so reads can un-swizzle (rule 21).
    const int srow = wave * 8 + (lane >> 3);                 // 0..31
    const int gchunk = (lane & 7) ^ ((lane >> 3) & 7);       // pre-swizzled chunk
    const unsigned short* Ag = A  + ((size_t)(bm * 128 + srow)) * 256 + gchunk * 8;
    const unsigned short* Bg = Bt + ((size_t)(bn * 128 + srow)) * 256 + gchunk * 8;
    unsigned short* laW0 = &lsA[0][wave * 512];
    unsigned short* lbW0 = &lsB[0][wave * 512];
    unsigned short* laW1 = &lsA[1][wave * 512];
    unsigned short* lbW1 = &lsB[1][wave * 512];

    // --- fragment addressing ---
    const int wrow = wave >> 1, wcol = wave & 1;
    const int fr = lane & 15;        // A-m / B-n row within 16x16 tile
    const int fq = lane >> 4;        // k-group 0..3
    const int fsw = fr & 7;          // read-side un-swizzle key
    const unsigned short* aB = &lsA[0][(wrow * 64 + fr) * 64];   // buffer 0 base
    const unsigned short* bB = &lsB[0][(wcol * 64 + fr) * 64];
    const int bufStride = 128 * 64;  // elements between buffer 0 and 1

    floatx4 acc[4][4] = {};          // acc[j(n)][i(m)], C^T fragments

    // prologue: stage k-tile 0 into buffer 0
    stage_tile(Ag, Bg, laW0, lbW0);
    __syncthreads();

    int cur = 0;
#pragma unroll
    for (int kt = 0; kt < 4; ++kt) {
        // prefetch next k-tile into the other buffer (issued before compute)
        if (kt < 3) {
            const int ko = (kt + 1) * 64;
            if (cur == 0) stage_tile(Ag + ko, Bg + ko, laW1, lbW1);
            else          stage_tile(Ag + ko, Bg + ko, laW0, lbW0);
        }

        const unsigned short* aT = aB + cur * bufStride;
        const unsigned short* bT = bB + cur * bufStride;
#pragma unroll
        for (int ks = 0; ks < 2; ++ks) {
            const int so = ((ks * 4 + fq) ^ fsw) * 8;   // un-swizzled 16B slot
            bf16x8 af[4], bv[4];
#pragma unroll
            for (int i = 0; i < 4; ++i) {
                af[i] = *(const bf16x8*)(const void*)(aT + i * 1024 + so);
                bv[i] = *(const bf16x8*)(const void*)(bT + i * 1024 + so);
            }
#pragma unroll
            for (int j = 0; j < 4; ++j)
#pragma unroll
                for (int i = 0; i < 4; ++i)
                    acc[j][i] = __builtin_amdgcn_mfma_f32_16x16x32_bf16(
                        bv[j], af[i], acc[j][i], 0, 0, 0);
        }
        __syncthreads();   // drains vmcnt(0): prefetched tile has landed
        cur ^= 1;
    }

    // --- epilogue ---
    // Swapped operands: D[n][m] = (A.B)^T fragment; C/D layout col=lane&15,
    // row=(lane>>4)*4+reg  =>  m = fr, n = fq*4 + reg.  Each lane owns 4
    // consecutive output columns -> one dwordx4 per (i,j).
    const int row0 = bm * 128 + wrow * 64 + fr;        // output row (m)
    const int col0 = bn * 128 + wcol * 64 + fq * 4;    // output col base (n)
#pragma unroll
    for (int i = 0; i < 4; ++i) {
        float* Cp = C + (size_t)(row0 + i * 16) * 4096 + col0;
#pragma unroll
        for (int j = 0; j < 4; ++j)
            *(floatx4*)(Cp + j * 16) = acc[j][i];
    }
}

extern "C" void kernel_launch(void* const* d_in, const int* in_sizes, int n_in,
                              void* d_out, int out_size, void* d_ws, size_t ws_size,
                              hipStream_t stream) {
    const float* x = (const float*)d_in[0];   // [16384, 256]
    const float* W = (const float*)d_in[1];   // [32, 4096, 8]
    float* out = (float*)d_out;               // [16384, 4096]

    unsigned short* xb = (unsigned short*)d_ws;            // 8 MB
    unsigned short* wb = xb + (size_t)16384 * 256;         // +2 MB = 10 MB total

    conv_x_kernel<<<2048, 256, 0, stream>>>(x, xb);
    pack_w_kernel<<<512, 256, 0, stream>>>(W, wb);

    dim3 grid(32, 128);   // bn = 4096/128, bm = 16384/128
    gemm_kernel<<<grid, 256, 0, stream>>>(xb, wb, out);
}